// Round 5
// baseline (364.613 us; speedup 1.0000x reference)
//
#include <hip/hip_runtime.h>

#define N_NODES 50000
#define N_EDGES 800000
#define ET (N_EDGES + N_NODES)   // 850000 incl. self loops
#define HEADS 8
#define NPAD 50048               // 782 blocks * 64 nodes
#define SCAN_NB 196              // ceil(50000/256)
#define CAP 96                   // LDS-cached edges per node (deg>CAP -> recompute)
#define LRS 1032                 // LDS A-tile row stride (halves, 16B-aligned)

typedef __attribute__((ext_vector_type(8))) _Float16 half8;
typedef __attribute__((ext_vector_type(2))) _Float16 half2v;
typedef __attribute__((ext_vector_type(4))) float f32x4;

// wave-local LDS fence: drains this wave's outstanding DS ops (same-wave
// cross-lane LDS write->read; consumers are ds_reads, ordered by "memory").
__device__ __forceinline__ void wave_lds_fence(){
  asm volatile("s_waitcnt lgkmcnt(0)" ::: "memory");
}

__device__ __forceinline__ int edge_src(const int* ei, int e, int is64){
  if (e >= N_EDGES) return e - N_EDGES;          // self loop
  return is64 ? ei[2*e] : ei[e];
}
__device__ __forceinline__ int edge_dst(const int* ei, int e, int is64){
  if (e >= N_EDGES) return e - N_EDGES;          // self loop
  return is64 ? ei[2*(N_EDGES + e)] : ei[N_EDGES + e];
}

// ---------------- init: zero deg/cnt + edge-index layout detection ----------------
__global__ void k_init(const int* __restrict__ ei, int* __restrict__ deg,
                       int* __restrict__ cnt, int* __restrict__ flag){
  int i = blockIdx.x*blockDim.x + threadIdx.x;
  if (i < N_NODES){ deg[i] = 0; cnt[i] = 0; }
  if (i == 0){
    int zeros = 0;
    for (int k = 0; k < 64; k++){
      if (ei[2*k + 1] == 0) zeros++;
    }
    *flag = (zeros >= 60) ? 1 : 0;   // 1 => int64 little-endian layout
  }
}

__global__ void k_degree(const int* __restrict__ ei, int* __restrict__ deg,
                         const int* __restrict__ flag){
  int e = blockIdx.x*blockDim.x + threadIdx.x;
  if (e >= ET) return;
  int is64 = *flag;
  int d = edge_dst(ei, e, is64);
  atomicAdd(&deg[d], 1);
}

// ---- 3-stage scan + contention-free degree counting sort (LDS histograms) ----
// hist_blk layout [blk][bin] so scan_carry's loops are COALESCED across threads.
__global__ void k_scan_part(const int* __restrict__ deg, int* __restrict__ loc,
                            int* __restrict__ part, int* __restrict__ hist_blk){
  __shared__ int lds[256];
  __shared__ int hl[256];
  int t = threadIdx.x, i = blockIdx.x*256 + t;
  int v = (i < N_NODES) ? deg[i] : 0;
  hl[t] = 0;
  __syncthreads();
  if (i < N_NODES){
    int b = v > 255 ? 255 : v;
    atomicAdd(&hl[255 - b], 1);          // LDS atomic: per-block, cheap
  }
  lds[t] = v;
  __syncthreads();
  for (int off = 1; off < 256; off <<= 1){
    int x = (t >= off) ? lds[t - off] : 0;
    __syncthreads();
    lds[t] += x;
    __syncthreads();
  }
  if (i < N_NODES) loc[i] = lds[t] - v;          // local exclusive
  if (t == 255) part[blockIdx.x] = lds[255];
  hist_blk[blockIdx.x*256 + t] = hl[t];          // blk-major [blk][bin]
}

__global__ void k_scan_carry(int* __restrict__ part, int* __restrict__ carry,
                             int* __restrict__ hist_blk){
  __shared__ int lds[256];
  int t = threadIdx.x;
  int v = (t < SCAN_NB) ? part[t] : 0;
  lds[t] = v;
  __syncthreads();
  for (int off = 1; off < 256; off <<= 1){
    int x = (t >= off) ? lds[t - off] : 0;
    __syncthreads();
    lds[t] += x;
    __syncthreads();
  }
  if (t < SCAN_NB) carry[t] = lds[t] - v;        // exclusive over blocks
  __syncthreads();
  // bin totals (thread t owns bin t); coalesced loads: hist_blk[b*256+t]
  int tot = 0;
  for (int b = 0; b < SCAN_NB; b++) tot += hist_blk[b*256 + t];
  lds[t] = tot;
  __syncthreads();
  for (int off = 1; off < 256; off <<= 1){
    int x = (t >= off) ? lds[t - off] : 0;
    __syncthreads();
    lds[t] += x;
    __syncthreads();
  }
  int run = lds[t] - tot;                        // exclusive base of bin t
  for (int b = 0; b < SCAN_NB; b++){
    int c = hist_blk[b*256 + t];
    hist_blk[b*256 + t] = run;                   // in-place: count -> offset
    run += c;
  }
}

__global__ void k_scan_add(const int* __restrict__ loc, const int* __restrict__ carry,
                           int* __restrict__ row_ptr, const int* __restrict__ deg,
                           const int* __restrict__ hist_blk, int* __restrict__ perm){
  __shared__ int hl[256];
  int t = threadIdx.x, i = blockIdx.x*256 + t;
  hl[t] = 0;
  __syncthreads();
  if (i < N_NODES){
    row_ptr[i] = loc[i] + carry[i >> 8];
    int d = deg[i]; if (d > 255) d = 255;
    int bin = 255 - d;
    int rank = atomicAdd(&hl[bin], 1);           // LDS atomic: local rank
    perm[hist_blk[blockIdx.x*256 + bin] + rank] = i;
  }
  if (i == 0) row_ptr[N_NODES] = ET;
}

__global__ void k_fill(const int* __restrict__ ei, const int* __restrict__ row_ptr,
                       int* __restrict__ cnt, int* __restrict__ col,
                       const int* __restrict__ flag){
  int e = blockIdx.x*blockDim.x + threadIdx.x;
  if (e >= ET) return;
  int is64 = *flag;
  int s = edge_src(ei, e, is64);
  int d = edge_dst(ei, e, is64);
  int pos = atomicAdd(&cnt[d], 1);
  col[row_ptr[d] + pos] = s;
}

// ---------------- merged weight prep (one launch) ----------------
// blocks [0,256): W2 pack; [256,320): W1 pack; [320,324): wtilde
__global__ void k_wprep(const float* __restrict__ W1, const float* __restrict__ W2,
                        const float* __restrict__ as2, const float* __restrict__ ad2,
                        _Float16* __restrict__ Bp1, _Float16* __restrict__ Bp,
                        float* __restrict__ ws2, float* __restrict__ wd2){
  int b = blockIdx.x;
  int t_ = threadIdx.x;
  if (b < 256){
    int t = b*256 + t_;
    int j = t & 7, lane = (t >> 3) & 63, nt = (t >> 9) & 3, kt = t >> 11;
    int k = kt*32 + (lane >> 4)*8 + j;
    int c = nt*16 + (lane & 15);
    int h = k >> 7, kk = k & 127;
    Bp[t] = (_Float16)(0.125f * W2[kk*512 + h*64 + c]);
  } else if (b < 320){
    int t = (b - 256)*256 + t_;
    int j = t & 7, lane = (t >> 3) & 63, nt = (t >> 9) & 7, kt = t >> 12;
    int k = kt*32 + (lane >> 4)*8 + j;
    int c = nt*16 + (lane & 15);
    Bp1[t] = (_Float16)W1[k*128 + c];
  } else {
    int t = (b - 320)*256 + t_;
    int k = t >> 3, h = t & 7;
    float s = 0.f, d = 0.f;
    for (int dd = 0; dd < 64; dd++){
      float w = W2[k*512 + h*64 + dd];
      s += w * as2[h*64 + dd];
      d += w * ad2[h*64 + dd];
    }
    ws2[h*128 + k] = s;
    wd2[h*128 + k] = d;
  }
}

// ------ layer 1 GEMM via MFMA: h1 = x @ W1 (fp16 out) + fused alpha1 logits ------
__global__ void __launch_bounds__(256) k_gemm1_mfma(
    const float* __restrict__ x, const _Float16* __restrict__ Bp1,
    _Float16* __restrict__ h1,
    const float* __restrict__ as1, const float* __restrict__ ad1,
    float* __restrict__ als1, float* __restrict__ ald1){
  int tid = threadIdx.x;
  int lane = tid & 63, wv = tid >> 6;
  int n0 = blockIdx.x*64 + wv*16;
  int rowA = n0 + (lane & 15);
  int koff = (lane >> 4)*8;
  const float* xr = x + (size_t)rowA*128 + koff;
  f32x4 acc[8];
  #pragma unroll
  for (int i = 0; i < 8; i++) acc[i] = (f32x4){0.f,0.f,0.f,0.f};
  bool inb = (rowA < N_NODES);
  #pragma unroll
  for (int kt = 0; kt < 4; kt++){
    half8 af;
    if (inb){
      float4 a0 = *(const float4*)(xr + kt*32);
      float4 a1 = *(const float4*)(xr + kt*32 + 4);
      af = (half8){(_Float16)a0.x,(_Float16)a0.y,(_Float16)a0.z,(_Float16)a0.w,
                   (_Float16)a1.x,(_Float16)a1.y,(_Float16)a1.z,(_Float16)a1.w};
    } else {
      af = (half8){0,0,0,0,0,0,0,0};
    }
    #pragma unroll
    for (int nt = 0; nt < 8; nt++){
      half8 bf = *(const half8*)(Bp1 + (((kt*8 + nt)*64 + lane) << 3));
      acc[nt] = __builtin_amdgcn_mfma_f32_16x16x32_f16(af, bf, acc[nt], 0, 0, 0);
    }
  }
  int m = lane & 15, q = lane >> 4;
  int r0 = n0 + q*4;               // C/D: col=lane&15, row=(lane>>4)*4+reg  [m89]
  #pragma unroll
  for (int nt = 0; nt < 8; nt++){
    int c = nt*16 + m;
    #pragma unroll
    for (int r = 0; r < 4; r++){
      int n = r0 + r;
      if (n < N_NODES) h1[(size_t)n*128 + c] = (_Float16)acc[nt][r];
    }
  }
  // fused alpha1: lane's acc[nt][r] is channel (nt*16+m) == head nt, pos m of row r0+r
  float as1v[8], ad1v[8];
  #pragma unroll
  for (int nt = 0; nt < 8; nt++){
    as1v[nt] = as1[nt*16 + m];
    ad1v[nt] = ad1[nt*16 + m];
  }
  #pragma unroll
  for (int r = 0; r < 4; r++){
    float vs[8], vd[8];
    #pragma unroll
    for (int nt = 0; nt < 8; nt++){
      vs[nt] = acc[nt][r]*as1v[nt];
      vd[nt] = acc[nt][r]*ad1v[nt];
      #pragma unroll
      for (int off = 1; off < 16; off <<= 1){
        vs[nt] += __shfl_xor(vs[nt], off, 64);
        vd[nt] += __shfl_xor(vd[nt], off, 64);
      }
    }
    int n = r0 + r;
    if (m == r && n < N_NODES){
      float4 v0; v0.x = vs[0]; v0.y = vs[1]; v0.z = vs[2]; v0.w = vs[3];
      float4 v1; v1.x = vs[4]; v1.y = vs[5]; v1.z = vs[6]; v1.w = vs[7];
      float4 w0; w0.x = vd[0]; w0.y = vd[1]; w0.z = vd[2]; w0.w = vd[3];
      float4 w1; w1.x = vd[4]; w1.y = vd[5]; w1.z = vd[6]; w1.w = vd[7];
      *(float4*)&als1[n*8]     = v0;
      *(float4*)&als1[n*8 + 4] = v1;
      *(float4*)&ald1[n*8]     = w0;
      *(float4*)&ald1[n*8 + 4] = w1;
    }
  }
}

// ===== layer 1: two-phase softmax+agg, LDS exp+col cache, fp32 acc =====
// perm-balanced nodes; NO cross-wave barrier (all LDS buffers are per-wave,
// wave_lds_fence suffices) -> waves fully independent, zero imbalance wait.
__global__ void k_attn_agg1(const _Float16* __restrict__ h1,
    const float* __restrict__ als, const float* __restrict__ ald,
    const int* __restrict__ row_ptr, const int* __restrict__ col,
    const float* __restrict__ bias, _Float16* __restrict__ hr,
    const float* __restrict__ ws2, const float* __restrict__ wd2,
    float* __restrict__ als2, float* __restrict__ ald2,
    const int* __restrict__ perm){
  __shared__ _Float16 ew_s[4][CAP*8];
  __shared__ int col_s[4][CAP];
  __shared__ _Float16 ot_s[4][132];
  int tid = threadIdx.x;
  int wv = tid >> 6, lane = tid & 63;
  int n = perm[blockIdx.x*4 + wv];        // grid exact: 12500*4 = 50000
  int beg = row_ptr[n], end = row_ptr[n+1];
  int deg = end - beg;
  int items = deg*8;
  int h = lane & 7;
  float ad = ald[n*8 + h];
  _Float16* es = ew_s[wv];
  int* cs = col_s[wv];
  float l = 0.f;
  int itc = items < CAP*8 ? items : CAP*8;
  int it = lane;
  for (; it < itc; it += 64){             // cached range: store es + col
    int e = it >> 3;
    int s = col[beg + e];
    float a = als[s*8 + h] + ad;
    a = (a > 0.f) ? a : 0.2f*a;
    float ex = __expf(a);
    es[it] = (_Float16)ex;
    if ((it & 7) == 0) cs[e] = s;
    l += ex;
  }
  for (; it < items; it += 64){           // rare overflow range
    int s = col[beg + (it >> 3)];
    float a = als[s*8 + h] + ad;
    a = (a > 0.f) ? a : 0.2f*a;
    l += __expf(a);
  }
  l += __shfl_xor(l, 8, 64);
  l += __shfl_xor(l, 16, 64);
  l += __shfl_xor(l, 32, 64);
  float inv = 1.f / (l + 1e-16f);
  wave_lds_fence();                       // own-wave LDS only: no __syncthreads
  int hh0 = lane >> 3;
  float invh = __shfl(inv, hh0, 64);
  const half2v* h2p = (const half2v*)h1;
  float ax = 0.f, ay = 0.f;
  int degc = deg < CAP ? deg : CAP;
  int j = 0;
  for (; j + 7 < degc; j += 8){
    int s[8]; float w[8]; half2v v[8];
    #pragma unroll
    for (int u = 0; u < 8; u++) s[u] = cs[j + u];
    #pragma unroll
    for (int u = 0; u < 8; u++) w[u] = (float)es[(j + u)*8 + hh0] * invh;
    #pragma unroll
    for (int u = 0; u < 8; u++) v[u] = h2p[(size_t)s[u]*64 + lane];
    #pragma unroll
    for (int u = 0; u < 8; u++){ ax += w[u]*(float)v[u].x; ay += w[u]*(float)v[u].y; }
  }
  for (; j < degc; j++){
    int s = cs[j];
    float w = (float)es[j*8 + hh0] * invh;
    half2v v = h2p[(size_t)s*64 + lane];
    ax += w*(float)v.x; ay += w*(float)v.y;
  }
  float adh = ald[n*8 + hh0];
  for (; j < deg; j++){                       // rare: deg > CAP
    int s = col[beg + j];
    float a = als[s*8 + hh0] + adh;
    a = (a > 0.f) ? a : 0.2f*a;
    float w = __expf(a)*invh;
    half2v v = h2p[(size_t)s*64 + lane];
    ax += w*(float)v.x; ay += w*(float)v.y;
  }
  float2 bb = ((const float2*)bias)[lane];
  float o0 = fmaxf(ax + bb.x, 0.f);
  float o1 = fmaxf(ay + bb.y, 0.f);
  half2v oo; oo.x = (_Float16)o0; oo.y = (_Float16)o1;
  ((half2v*)hr)[(size_t)n*64 + lane] = oo;
  // fused alpha2 via LDS transpose: lane -> (head hh=lane>>3, segment seg=lane&7)
  ((half2v*)&ot_s[wv][0])[lane] = oo;     // same-wave LDS
  wave_lds_fence();
  int hh = lane >> 3, seg = lane & 7;
  const half2v* otp = (const half2v*)&ot_s[wv][0];
  const float* wsr = ws2 + hh*128 + seg*16;
  const float* wdr = wd2 + hh*128 + seg*16;
  float vs = 0.f, vd = 0.f;
  #pragma unroll
  for (int i = 0; i < 8; i++){
    half2v v = otp[seg*8 + i];
    float vx = (float)v.x, vy = (float)v.y;
    vs += vx*wsr[2*i] + vy*wsr[2*i + 1];
    vd += vx*wdr[2*i] + vy*wdr[2*i + 1];
  }
  vs += __shfl_xor(vs, 1, 64); vd += __shfl_xor(vd, 1, 64);
  vs += __shfl_xor(vs, 2, 64); vd += __shfl_xor(vd, 2, 64);
  vs += __shfl_xor(vs, 4, 64); vd += __shfl_xor(vd, 4, 64);
  if (seg == 0){
    als2[n*8 + hh] = vs;
    ald2[n*8 + hh] = vd;
  }
}

// ===== layer 2 FUSED: softmax+agg (16 waves = 16 nodes) + output MFMA GEMM =====
// perm-balanced; mid barrier is a wave-local fence (per-wave LDS only); phase-2
// gather unrolled 8-deep (VGPR headroom, occupancy LDS-capped at 2 blk/CU).
// Single remaining __syncthreads before the MFMA epilogue (cross-wave A-tile).
__global__ void __launch_bounds__(1024) k_attn_agg2(const _Float16* __restrict__ hr,
    const float* __restrict__ als, const float* __restrict__ ald,
    const int* __restrict__ row_ptr, const int* __restrict__ col,
    const _Float16* __restrict__ Bp, const float* __restrict__ b2,
    float* __restrict__ outp, const int* __restrict__ perm){
  __shared__ _Float16 ew_s[16][CAP*8];
  __shared__ int col_s[16][CAP];
  __shared__ _Float16 at[16*LRS];
  __shared__ int nid_s[16];
  int tid = threadIdx.x;
  int wv = tid >> 6, lane = tid & 63;
  int n = perm[blockIdx.x*16 + wv];       // grid exact: 3125*16 = 50000
  if (lane == 0) nid_s[wv] = n;
  int beg = row_ptr[n], end = row_ptr[n+1];
  int deg = end - beg;
  int items = deg*8;
  int h = lane & 7;
  float ad = ald[n*8 + h];
  _Float16* es = ew_s[wv];
  int* cs = col_s[wv];
  float l = 0.f;
  int itc = items < CAP*8 ? items : CAP*8;
  int it = lane;
  for (; it < itc; it += 64){
    int e = it >> 3;
    int s = col[beg + e];
    float a = als[s*8 + h] + ad;
    a = (a > 0.f) ? a : 0.2f*a;
    float ex = __expf(a);
    es[it] = (_Float16)ex;
    if ((it & 7) == 0) cs[e] = s;
    l += ex;
  }
  for (; it < items; it += 64){
    int s = col[beg + (it >> 3)];
    float a = als[s*8 + h] + ad;
    a = (a > 0.f) ? a : 0.2f*a;
    l += __expf(a);
  }
  l += __shfl_xor(l, 8, 64);
  l += __shfl_xor(l, 16, 64);
  l += __shfl_xor(l, 32, 64);
  float inv = 1.f / (l + 1e-16f);   // for head lane&7 (lanes with same lane&7 agree)
  wave_lds_fence();                 // own-wave LDS only: no cross-wave barrier here
  int hp = lane >> 4, cb = lane & 15;
  float invA = __shfl(inv, 2*hp, 64);       // inv for head 2hp   (held by lane 2hp)
  float invB = __shfl(inv, 2*hp + 1, 64);   // inv for head 2hp+1
  half2v inv2; inv2.x = (_Float16)invA; inv2.y = (_Float16)invB;
  half2v acc_a[4], acc_b[4];
  #pragma unroll
  for (int i = 0; i < 4; i++){
    acc_a[i] = (half2v){(_Float16)0.f, (_Float16)0.f};
    acc_b[i] = (half2v){(_Float16)0.f, (_Float16)0.f};
  }
  int degc = deg < CAP ? deg : CAP;
  const _Float16* esw = es + 2*hp;          // per-lane weight base (both heads, u32)
  int j = 0;
  for (; j + 7 < degc; j += 8){             // 8-deep: maximize gathers in flight
    int s[8];
    #pragma unroll
    for (int u = 0; u < 8; u++) s[u] = cs[j + u];
    half2v w[8];
    #pragma unroll
    for (int u = 0; u < 8; u++) w[u] = *(const half2v*)(esw + (j + u)*8) * inv2;
    half8 v[8];
    #pragma unroll
    for (int u = 0; u < 8; u++) v[u] = *(const half8*)(hr + (size_t)s[u]*128 + cb*8);
    #pragma unroll
    for (int u = 0; u < 8; u++){
      #pragma unroll
      for (int k = 0; k < 4; k++){
        half2v t = (half2v){v[u][2*k], v[u][2*k+1]};
        acc_a[k] += (half2v){w[u].x, w[u].x} * t;
        acc_b[k] += (half2v){w[u].y, w[u].y} * t;
      }
    }
  }
  for (; j < degc; j++){
    int s = cs[j];
    half2v w = *(const half2v*)(esw + j*8) * inv2;
    half8 v = *(const half8*)(hr + (size_t)s*128 + cb*8);
    #pragma unroll
    for (int k = 0; k < 4; k++){
      half2v t = (half2v){v[2*k], v[2*k+1]};
      acc_a[k] += (half2v){w.x, w.x} * t;
      acc_b[k] += (half2v){w.y, w.y} * t;
    }
  }
  if (deg > CAP){                             // rare: deg > CAP, recompute weights
    float2 adv = *(const float2*)(ald + (size_t)n*8 + 2*hp);
    for (; j < deg; j++){
      int s = col[beg + j];
      float2 alv = *(const float2*)(als + (size_t)s*8 + 2*hp);
      float a0 = alv.x + adv.x; a0 = (a0 > 0.f) ? a0 : 0.2f*a0;
      float a1 = alv.y + adv.y; a1 = (a1 > 0.f) ? a1 : 0.2f*a1;
      _Float16 w0 = (_Float16)(__expf(a0)*invA);
      _Float16 w1 = (_Float16)(__expf(a1)*invB);
      half8 v = *(const half8*)(hr + (size_t)s*128 + cb*8);
      #pragma unroll
      for (int k = 0; k < 4; k++){
        half2v t = (half2v){v[2*k], v[2*k+1]};
        acc_a[k] += (half2v){w0, w0} * t;
        acc_b[k] += (half2v){w1, w1} * t;
      }
    }
  }
  // write normalized rows into the LDS A-tile: head 2hp and 2hp+1, channels cb*8..
  _Float16* ar = at + wv*LRS + (2*hp)*128 + cb*8;
  half8 oa, ob;
  #pragma unroll
  for (int k = 0; k < 4; k++){
    oa[2*k] = acc_a[k].x; oa[2*k+1] = acc_a[k].y;
    ob[2*k] = acc_b[k].x; ob[2*k+1] = acc_b[k].y;
  }
  *(half8*)ar = oa;
  *(half8*)(ar + 128) = ob;
  __syncthreads();
  if (wv >= 4) return;
  // MFMA epilogue: wave wv = output col-tile nt; A from LDS, Bp L2-hot
  int m = lane & 15, q = lane >> 4;
  const _Float16* arow = at + m*LRS + q*8;
  f32x4 cacc = (f32x4){0.f,0.f,0.f,0.f};
  #pragma unroll 4
  for (int kt = 0; kt < 32; kt++){
    half8 af = *(const half8*)(arow + kt*32);
    half8 bf = *(const half8*)(Bp + (((kt*4 + wv)*64 + lane) << 3));
    cacc = __builtin_amdgcn_mfma_f32_16x16x32_f16(af, bf, cacc, 0, 0, 0);
  }
  int c = wv*16 + m;
  float bb = b2[c];
  #pragma unroll
  for (int r = 0; r < 4; r++){
    int nrow = nid_s[q*4 + r];            // true node id (perm'd rows)
    outp[(size_t)nrow*64 + c] = cacc[r] + bb;
  }
}

extern "C" void kernel_launch(void* const* d_in, const int* in_sizes, int n_in,
                              void* d_out, int out_size, void* d_ws, size_t ws_size,
                              hipStream_t stream){
  const float* x   = (const float*)d_in[0];
  const int*   ei  = (const int*)d_in[1];
  const float* W1  = (const float*)d_in[2];
  const float* as1 = (const float*)d_in[3];
  const float* ad1 = (const float*)d_in[4];
  const float* b1  = (const float*)d_in[5];
  const float* W2  = (const float*)d_in[6];
  const float* as2 = (const float*)d_in[7];
  const float* ad2 = (const float*)d_in[8];
  const float* b2  = (const float*)d_in[9];
  float* outp = (float*)d_out;

  char* p = (char*)d_ws;
  auto alloc = [&](size_t bytes) -> void* {
    void* r = (void*)p;
    p += (bytes + 255) & ~(size_t)255;
    return r;
  };
  _Float16* h1  = (_Float16*)alloc((size_t)NPAD*128*2);          // [N,128] fp16
  _Float16* hr  = (_Float16*)alloc((size_t)N_NODES*128*2);       // [N,128] fp16
  float* als1 = (float*)alloc((size_t)N_NODES*8*4);
  float* ald1 = (float*)alloc((size_t)N_NODES*8*4);
  float* als2 = (float*)alloc((size_t)N_NODES*8*4);
  float* ald2 = (float*)alloc((size_t)N_NODES*8*4);
  int* row_ptr = (int*)alloc((size_t)(N_NODES+1)*4);
  int* deg  = (int*)alloc((size_t)N_NODES*4);
  int* cnt  = (int*)alloc((size_t)N_NODES*4);
  int* col  = (int*)alloc((size_t)ET*4);
  int* loc  = (int*)alloc((size_t)N_NODES*4);
  int* part = (int*)alloc(256*4);
  int* carry= (int*)alloc(256*4);
  int* flag = (int*)alloc(256);
  int* hist_blk = (int*)alloc((size_t)256*SCAN_NB*4);   // [blk][bin] counts->offsets
  int* perm = (int*)alloc((size_t)N_NODES*4);
  float* ws2 = (float*)alloc(1024*4);
  float* wd2 = (float*)alloc(1024*4);
  _Float16* Bp1 = (_Float16*)alloc((size_t)16384*2);
  _Float16* Bp  = (_Float16*)alloc((size_t)65536*2);

  dim3 b256(256);
  // CSR build + contention-free degree counting sort (folded into the scans)
  k_init<<<(N_NODES+255)/256, b256, 0, stream>>>(ei, deg, cnt, flag);
  k_degree<<<(ET+255)/256, b256, 0, stream>>>(ei, deg, flag);
  k_scan_part<<<SCAN_NB, b256, 0, stream>>>(deg, loc, part, hist_blk);
  k_scan_carry<<<1, b256, 0, stream>>>(part, carry, hist_blk);
  k_scan_add<<<SCAN_NB, b256, 0, stream>>>(loc, carry, row_ptr, deg, hist_blk, perm);
  k_fill<<<(ET+255)/256, b256, 0, stream>>>(ei, row_ptr, cnt, col, flag);
  // merged weight prep
  k_wprep<<<324, b256, 0, stream>>>(W1, W2, as2, ad2, Bp1, Bp, ws2, wd2);

  // layer 1 (alpha1 fused into the GEMM epilogue)
  k_gemm1_mfma<<<NPAD/64, b256, 0, stream>>>(x, Bp1, h1, as1, ad1, als1, ald1);
  k_attn_agg1<<<N_NODES/4, b256, 0, stream>>>(h1, als1, ald1, row_ptr, col,
                                              b1, hr, ws2, wd2, als2, ald2, perm);
  // layer 2: fused softmax+agg+output-GEMM
  k_attn_agg2<<<N_NODES/16, dim3(1024), 0, stream>>>(hr, als2, ald2, row_ptr, col,
                                                     Bp, b2, outp, perm);
}

// Round 6
// 326.573 us; speedup vs baseline: 1.1165x; 1.1165x over previous
//
#include <hip/hip_runtime.h>

#define N_NODES 50000
#define N_EDGES 800000
#define ET (N_EDGES + N_NODES)   // 850000 incl. self loops
#define HEADS 8
#define NPAD 50048               // 782 blocks * 64 nodes
#define SCAN_NB 196              // ceil(50000/256)
#define CAP 96                   // LDS-cached edges per node (deg>CAP -> recompute)
#define LRS 1032                 // LDS A-tile row stride (halves, 16B-aligned)
#define NB_DEG 3321              // ceil(850000/256)
#define NB_GEMM1 782             // NPAD/64

typedef __attribute__((ext_vector_type(8))) _Float16 half8;
typedef __attribute__((ext_vector_type(2))) _Float16 half2v;
typedef __attribute__((ext_vector_type(4))) float f32x4;

// wave-local LDS fence: drains this wave's outstanding DS ops (same-wave
// cross-lane LDS write->read; consumers are ds_reads, ordered by "memory").
__device__ __forceinline__ void wave_lds_fence(){
  asm volatile("s_waitcnt lgkmcnt(0)" ::: "memory");
}

__device__ __forceinline__ int edge_src(const int* ei, int e, int is64){
  if (e >= N_EDGES) return e - N_EDGES;          // self loop
  return is64 ? ei[2*e] : ei[e];
}
__device__ __forceinline__ int edge_dst(const int* ei, int e, int is64){
  if (e >= N_EDGES) return e - N_EDGES;          // self loop
  return is64 ? ei[2*(N_EDGES + e)] : ei[N_EDGES + e];
}

// ======== launch 1: init (zero deg/cnt + layout probe) FUSED with wprep ========
// blocks [0,196): init; [196,452): W2 pack; [452,516): W1 pack; [516,520): wtilde
__global__ void k_init_wprep(const int* __restrict__ ei, int* __restrict__ deg,
                             int* __restrict__ cnt, int* __restrict__ flag,
                             const float* __restrict__ W1, const float* __restrict__ W2,
                             const float* __restrict__ as2, const float* __restrict__ ad2,
                             _Float16* __restrict__ Bp1, _Float16* __restrict__ Bp,
                             float* __restrict__ ws2, float* __restrict__ wd2){
  int b = blockIdx.x;
  int t_ = threadIdx.x;
  if (b < SCAN_NB){
    int i = b*256 + t_;
    if (i < N_NODES){ deg[i] = 0; cnt[i] = 0; }
    if (i == 0){
      int zeros = 0;
      for (int k = 0; k < 64; k++){
        if (ei[2*k + 1] == 0) zeros++;
      }
      *flag = (zeros >= 60) ? 1 : 0;   // 1 => int64 little-endian layout
    }
  } else if (b < SCAN_NB + 256){
    int t = (b - SCAN_NB)*256 + t_;
    int j = t & 7, lane = (t >> 3) & 63, nt = (t >> 9) & 3, kt = t >> 11;
    int k = kt*32 + (lane >> 4)*8 + j;
    int c = nt*16 + (lane & 15);
    int h = k >> 7, kk = k & 127;
    Bp[t] = (_Float16)(0.125f * W2[kk*512 + h*64 + c]);
  } else if (b < SCAN_NB + 320){
    int t = (b - SCAN_NB - 256)*256 + t_;
    int j = t & 7, lane = (t >> 3) & 63, nt = (t >> 9) & 7, kt = t >> 12;
    int k = kt*32 + (lane >> 4)*8 + j;
    int c = nt*16 + (lane & 15);
    Bp1[t] = (_Float16)W1[k*128 + c];
  } else {
    int t = (b - SCAN_NB - 320)*256 + t_;
    int k = t >> 3, h = t & 7;
    float s = 0.f, d = 0.f;
    for (int dd = 0; dd < 64; dd++){
      float w = W2[k*512 + h*64 + dd];
      s += w * as2[h*64 + dd];
      d += w * ad2[h*64 + dd];
    }
    ws2[h*128 + k] = s;
    wd2[h*128 + k] = d;
  }
}

// ======== launch 2: degree histogram FUSED with layer-1 GEMM (independent) ========
// blocks [0,NB_DEG): degree atomics; [NB_DEG, NB_DEG+NB_GEMM1): h1 = x@W1 + alpha1.
__global__ void __launch_bounds__(256) k_deg_gemm1(
    const int* __restrict__ ei, int* __restrict__ deg, const int* __restrict__ flag,
    const float* __restrict__ x, const _Float16* __restrict__ Bp1,
    _Float16* __restrict__ h1,
    const float* __restrict__ as1, const float* __restrict__ ad1,
    float* __restrict__ als1, float* __restrict__ ald1){
  if (blockIdx.x < NB_DEG){
    int e = blockIdx.x*blockDim.x + threadIdx.x;
    if (e >= ET) return;
    int is64 = *flag;
    int d = edge_dst(ei, e, is64);
    atomicAdd(&deg[d], 1);
    return;
  }
  int bid = blockIdx.x - NB_DEG;
  int tid = threadIdx.x;
  int lane = tid & 63, wv = tid >> 6;
  int n0 = bid*64 + wv*16;
  int rowA = n0 + (lane & 15);
  int koff = (lane >> 4)*8;
  const float* xr = x + (size_t)rowA*128 + koff;
  f32x4 acc[8];
  #pragma unroll
  for (int i = 0; i < 8; i++) acc[i] = (f32x4){0.f,0.f,0.f,0.f};
  bool inb = (rowA < N_NODES);
  #pragma unroll
  for (int kt = 0; kt < 4; kt++){
    half8 af;
    if (inb){
      float4 a0 = *(const float4*)(xr + kt*32);
      float4 a1 = *(const float4*)(xr + kt*32 + 4);
      af = (half8){(_Float16)a0.x,(_Float16)a0.y,(_Float16)a0.z,(_Float16)a0.w,
                   (_Float16)a1.x,(_Float16)a1.y,(_Float16)a1.z,(_Float16)a1.w};
    } else {
      af = (half8){0,0,0,0,0,0,0,0};
    }
    #pragma unroll
    for (int nt = 0; nt < 8; nt++){
      half8 bf = *(const half8*)(Bp1 + (((kt*8 + nt)*64 + lane) << 3));
      acc[nt] = __builtin_amdgcn_mfma_f32_16x16x32_f16(af, bf, acc[nt], 0, 0, 0);
    }
  }
  int m = lane & 15, q = lane >> 4;
  int r0 = n0 + q*4;               // C/D: col=lane&15, row=(lane>>4)*4+reg  [m89]
  #pragma unroll
  for (int nt = 0; nt < 8; nt++){
    int c = nt*16 + m;
    #pragma unroll
    for (int r = 0; r < 4; r++){
      int n = r0 + r;
      if (n < N_NODES) h1[(size_t)n*128 + c] = (_Float16)acc[nt][r];
    }
  }
  // fused alpha1: lane's acc[nt][r] is channel (nt*16+m) == head nt, pos m of row r0+r
  float as1v[8], ad1v[8];
  #pragma unroll
  for (int nt = 0; nt < 8; nt++){
    as1v[nt] = as1[nt*16 + m];
    ad1v[nt] = ad1[nt*16 + m];
  }
  #pragma unroll
  for (int r = 0; r < 4; r++){
    float vs[8], vd[8];
    #pragma unroll
    for (int nt = 0; nt < 8; nt++){
      vs[nt] = acc[nt][r]*as1v[nt];
      vd[nt] = acc[nt][r]*ad1v[nt];
      #pragma unroll
      for (int off = 1; off < 16; off <<= 1){
        vs[nt] += __shfl_xor(vs[nt], off, 64);
        vd[nt] += __shfl_xor(vd[nt], off, 64);
      }
    }
    int n = r0 + r;
    if (m == r && n < N_NODES){
      float4 v0; v0.x = vs[0]; v0.y = vs[1]; v0.z = vs[2]; v0.w = vs[3];
      float4 v1; v1.x = vs[4]; v1.y = vs[5]; v1.z = vs[6]; v1.w = vs[7];
      float4 w0; w0.x = vd[0]; w0.y = vd[1]; w0.z = vd[2]; w0.w = vd[3];
      float4 w1; w1.x = vd[4]; w1.y = vd[5]; w1.z = vd[6]; w1.w = vd[7];
      *(float4*)&als1[n*8]     = v0;
      *(float4*)&als1[n*8 + 4] = v1;
      *(float4*)&ald1[n*8]     = w0;
      *(float4*)&ald1[n*8 + 4] = w1;
    }
  }
}

// ---- 3-stage scan (R1 form, no perm machinery) ----
__global__ void k_scan_part(const int* __restrict__ deg, int* __restrict__ loc,
                            int* __restrict__ part){
  __shared__ int lds[256];
  int t = threadIdx.x, i = blockIdx.x*256 + t;
  int v = (i < N_NODES) ? deg[i] : 0;
  lds[t] = v;
  __syncthreads();
  for (int off = 1; off < 256; off <<= 1){
    int x = (t >= off) ? lds[t - off] : 0;
    __syncthreads();
    lds[t] += x;
    __syncthreads();
  }
  if (i < N_NODES) loc[i] = lds[t] - v;          // local exclusive
  if (t == 255) part[blockIdx.x] = lds[255];
}

__global__ void k_scan_carry(int* __restrict__ part, int* __restrict__ carry){
  __shared__ int lds[256];
  int t = threadIdx.x;
  int v = (t < SCAN_NB) ? part[t] : 0;
  lds[t] = v;
  __syncthreads();
  for (int off = 1; off < 256; off <<= 1){
    int x = (t >= off) ? lds[t - off] : 0;
    __syncthreads();
    lds[t] += x;
    __syncthreads();
  }
  if (t < SCAN_NB) carry[t] = lds[t] - v;        // exclusive over blocks
}

__global__ void k_scan_add(const int* __restrict__ loc, const int* __restrict__ carry,
                           int* __restrict__ row_ptr){
  int i = blockIdx.x*blockDim.x + threadIdx.x;
  if (i < N_NODES) row_ptr[i] = loc[i] + carry[i >> 8];
  if (i == 0) row_ptr[N_NODES] = ET;
}

__global__ void k_fill(const int* __restrict__ ei, const int* __restrict__ row_ptr,
                       int* __restrict__ cnt, int* __restrict__ col,
                       const int* __restrict__ flag){
  int e = blockIdx.x*blockDim.x + threadIdx.x;
  if (e >= ET) return;
  int is64 = *flag;
  int s = edge_src(ei, e, is64);
  int d = edge_dst(ei, e, is64);
  int pos = atomicAdd(&cnt[d], 1);
  col[row_ptr[d] + pos] = s;
}

// ===== layer 1: two-phase softmax+agg, LDS exp+col cache, fp32 acc =====
// NO cross-wave barrier (all LDS buffers per-wave; wave_lds_fence suffices).
__global__ void k_attn_agg1(const _Float16* __restrict__ h1,
    const float* __restrict__ als, const float* __restrict__ ald,
    const int* __restrict__ row_ptr, const int* __restrict__ col,
    const float* __restrict__ bias, _Float16* __restrict__ hr,
    const float* __restrict__ ws2, const float* __restrict__ wd2,
    float* __restrict__ als2, float* __restrict__ ald2){
  __shared__ _Float16 ew_s[4][CAP*8];
  __shared__ int col_s[4][CAP];
  __shared__ _Float16 ot_s[4][132];
  int tid = threadIdx.x;
  int wv = tid >> 6, lane = tid & 63;
  int n = blockIdx.x*4 + wv;              // grid exact: 12500*4 = 50000
  int beg = row_ptr[n], end = row_ptr[n+1];
  int deg = end - beg;
  int items = deg*8;
  int h = lane & 7;
  float ad = ald[n*8 + h];
  _Float16* es = ew_s[wv];
  int* cs = col_s[wv];
  float l = 0.f;
  int itc = items < CAP*8 ? items : CAP*8;
  int it = lane;
  for (; it < itc; it += 64){             // cached range: store es + col
    int e = it >> 3;
    int s = col[beg + e];
    float a = als[s*8 + h] + ad;
    a = (a > 0.f) ? a : 0.2f*a;
    float ex = __expf(a);
    es[it] = (_Float16)ex;
    if ((it & 7) == 0) cs[e] = s;
    l += ex;
  }
  for (; it < items; it += 64){           // rare overflow range
    int s = col[beg + (it >> 3)];
    float a = als[s*8 + h] + ad;
    a = (a > 0.f) ? a : 0.2f*a;
    l += __expf(a);
  }
  l += __shfl_xor(l, 8, 64);
  l += __shfl_xor(l, 16, 64);
  l += __shfl_xor(l, 32, 64);
  float inv = 1.f / (l + 1e-16f);
  wave_lds_fence();                       // own-wave LDS only: no __syncthreads
  int hh0 = lane >> 3;
  float invh = __shfl(inv, hh0, 64);
  const half2v* h2p = (const half2v*)h1;
  float ax = 0.f, ay = 0.f;
  int degc = deg < CAP ? deg : CAP;
  int j = 0;
  for (; j + 7 < degc; j += 8){
    int s[8]; float w[8]; half2v v[8];
    #pragma unroll
    for (int u = 0; u < 8; u++) s[u] = cs[j + u];
    #pragma unroll
    for (int u = 0; u < 8; u++) w[u] = (float)es[(j + u)*8 + hh0] * invh;
    #pragma unroll
    for (int u = 0; u < 8; u++) v[u] = h2p[(size_t)s[u]*64 + lane];
    #pragma unroll
    for (int u = 0; u < 8; u++){ ax += w[u]*(float)v[u].x; ay += w[u]*(float)v[u].y; }
  }
  for (; j < degc; j++){
    int s = cs[j];
    float w = (float)es[j*8 + hh0] * invh;
    half2v v = h2p[(size_t)s*64 + lane];
    ax += w*(float)v.x; ay += w*(float)v.y;
  }
  float adh = ald[n*8 + hh0];
  for (; j < deg; j++){                       // rare: deg > CAP
    int s = col[beg + j];
    float a = als[s*8 + hh0] + adh;
    a = (a > 0.f) ? a : 0.2f*a;
    float w = __expf(a)*invh;
    half2v v = h2p[(size_t)s*64 + lane];
    ax += w*(float)v.x; ay += w*(float)v.y;
  }
  float2 bb = ((const float2*)bias)[lane];
  float o0 = fmaxf(ax + bb.x, 0.f);
  float o1 = fmaxf(ay + bb.y, 0.f);
  half2v oo; oo.x = (_Float16)o0; oo.y = (_Float16)o1;
  ((half2v*)hr)[(size_t)n*64 + lane] = oo;
  // fused alpha2 via LDS transpose: lane -> (head hh=lane>>3, segment seg=lane&7)
  ((half2v*)&ot_s[wv][0])[lane] = oo;     // same-wave LDS
  wave_lds_fence();
  int hh = lane >> 3, seg = lane & 7;
  const half2v* otp = (const half2v*)&ot_s[wv][0];
  const float* wsr = ws2 + hh*128 + seg*16;
  const float* wdr = wd2 + hh*128 + seg*16;
  float vs = 0.f, vd = 0.f;
  #pragma unroll
  for (int i = 0; i < 8; i++){
    half2v v = otp[seg*8 + i];
    float vx = (float)v.x, vy = (float)v.y;
    vs += vx*wsr[2*i] + vy*wsr[2*i + 1];
    vd += vx*wdr[2*i] + vy*wdr[2*i + 1];
  }
  vs += __shfl_xor(vs, 1, 64); vd += __shfl_xor(vd, 1, 64);
  vs += __shfl_xor(vs, 2, 64); vd += __shfl_xor(vd, 2, 64);
  vs += __shfl_xor(vs, 4, 64); vd += __shfl_xor(vd, 4, 64);
  if (seg == 0){
    als2[n*8 + hh] = vs;
    ald2[n*8 + hh] = vd;
  }
}

// ===== layer 2 FUSED: softmax+agg (16 waves = 16 nodes) + output MFMA GEMM =====
// Two-phase with LDS exp table (dedups exps 16x vs single-pass, R4 lesson);
// mid barrier = wave-local fence; phase-2 unroll-4 (28 VGPR sweet spot, R5 lesson).
__global__ void __launch_bounds__(1024) k_attn_agg2(const _Float16* __restrict__ hr,
    const float* __restrict__ als, const float* __restrict__ ald,
    const int* __restrict__ row_ptr, const int* __restrict__ col,
    const _Float16* __restrict__ Bp, const float* __restrict__ b2,
    float* __restrict__ outp){
  __shared__ _Float16 ew_s[16][CAP*8];
  __shared__ int col_s[16][CAP];
  __shared__ _Float16 at[16*LRS];
  int tid = threadIdx.x;
  int wv = tid >> 6, lane = tid & 63;
  int n = blockIdx.x*16 + wv;             // grid exact: 3125*16 = 50000
  int beg = row_ptr[n], end = row_ptr[n+1];
  int deg = end - beg;
  int items = deg*8;
  int h = lane & 7;
  float ad = ald[n*8 + h];
  _Float16* es = ew_s[wv];
  int* cs = col_s[wv];
  float l = 0.f;
  int itc = items < CAP*8 ? items : CAP*8;
  int it = lane;
  for (; it < itc; it += 64){
    int e = it >> 3;
    int s = col[beg + e];
    float a = als[s*8 + h] + ad;
    a = (a > 0.f) ? a : 0.2f*a;
    float ex = __expf(a);
    es[it] = (_Float16)ex;
    if ((it & 7) == 0) cs[e] = s;
    l += ex;
  }
  for (; it < items; it += 64){
    int s = col[beg + (it >> 3)];
    float a = als[s*8 + h] + ad;
    a = (a > 0.f) ? a : 0.2f*a;
    l += __expf(a);
  }
  l += __shfl_xor(l, 8, 64);
  l += __shfl_xor(l, 16, 64);
  l += __shfl_xor(l, 32, 64);
  float inv = 1.f / (l + 1e-16f);   // for head lane&7 (lanes with same lane&7 agree)
  wave_lds_fence();                 // own-wave LDS only: no cross-wave barrier here
  int hp = lane >> 4, cb = lane & 15;
  float invA = __shfl(inv, 2*hp, 64);       // inv for head 2hp   (held by lane 2hp)
  float invB = __shfl(inv, 2*hp + 1, 64);   // inv for head 2hp+1
  half2v inv2; inv2.x = (_Float16)invA; inv2.y = (_Float16)invB;
  half2v acc_a[4], acc_b[4];
  #pragma unroll
  for (int i = 0; i < 4; i++){
    acc_a[i] = (half2v){(_Float16)0.f, (_Float16)0.f};
    acc_b[i] = (half2v){(_Float16)0.f, (_Float16)0.f};
  }
  int degc = deg < CAP ? deg : CAP;
  const _Float16* esw = es + 2*hp;          // per-lane weight base (both heads, u32)
  int j = 0;
  for (; j + 3 < degc; j += 4){
    int s0 = cs[j], s1 = cs[j+1], s2 = cs[j+2], s3 = cs[j+3];
    half2v w0 = *(const half2v*)(esw + (j+0)*8) * inv2;
    half2v w1 = *(const half2v*)(esw + (j+1)*8) * inv2;
    half2v w2 = *(const half2v*)(esw + (j+2)*8) * inv2;
    half2v w3 = *(const half2v*)(esw + (j+3)*8) * inv2;
    half8 v0 = *(const half8*)(hr + (size_t)s0*128 + cb*8);
    half8 v1 = *(const half8*)(hr + (size_t)s1*128 + cb*8);
    half8 v2 = *(const half8*)(hr + (size_t)s2*128 + cb*8);
    half8 v3 = *(const half8*)(hr + (size_t)s3*128 + cb*8);
    #pragma unroll
    for (int k = 0; k < 4; k++){
      half2v t;
      t = (half2v){v0[2*k], v0[2*k+1]};
      acc_a[k] += (half2v){w0.x, w0.x} * t;
      acc_b[k] += (half2v){w0.y, w0.y} * t;
      t = (half2v){v1[2*k], v1[2*k+1]};
      acc_a[k] += (half2v){w1.x, w1.x} * t;
      acc_b[k] += (half2v){w1.y, w1.y} * t;
      t = (half2v){v2[2*k], v2[2*k+1]};
      acc_a[k] += (half2v){w2.x, w2.x} * t;
      acc_b[k] += (half2v){w2.y, w2.y} * t;
      t = (half2v){v3[2*k], v3[2*k+1]};
      acc_a[k] += (half2v){w3.x, w3.x} * t;
      acc_b[k] += (half2v){w3.y, w3.y} * t;
    }
  }
  for (; j < degc; j++){
    int s = cs[j];
    half2v w = *(const half2v*)(esw + j*8) * inv2;
    half8 v = *(const half8*)(hr + (size_t)s*128 + cb*8);
    #pragma unroll
    for (int k = 0; k < 4; k++){
      half2v t = (half2v){v[2*k], v[2*k+1]};
      acc_a[k] += (half2v){w.x, w.x} * t;
      acc_b[k] += (half2v){w.y, w.y} * t;
    }
  }
  if (deg > CAP){                             // rare: deg > CAP, recompute weights
    float2 adv = *(const float2*)(ald + (size_t)n*8 + 2*hp);
    for (; j < deg; j++){
      int s = col[beg + j];
      float2 alv = *(const float2*)(als + (size_t)s*8 + 2*hp);
      float a0 = alv.x + adv.x; a0 = (a0 > 0.f) ? a0 : 0.2f*a0;
      float a1 = alv.y + adv.y; a1 = (a1 > 0.f) ? a1 : 0.2f*a1;
      _Float16 w0 = (_Float16)(__expf(a0)*invA);
      _Float16 w1 = (_Float16)(__expf(a1)*invB);
      half8 v = *(const half8*)(hr + (size_t)s*128 + cb*8);
      #pragma unroll
      for (int k = 0; k < 4; k++){
        half2v t = (half2v){v[2*k], v[2*k+1]};
        acc_a[k] += (half2v){w0, w0} * t;
        acc_b[k] += (half2v){w1, w1} * t;
      }
    }
  }
  // write normalized rows into the LDS A-tile: head 2hp and 2hp+1, channels cb*8..
  _Float16* ar = at + wv*LRS + (2*hp)*128 + cb*8;
  half8 oa, ob;
  #pragma unroll
  for (int k = 0; k < 4; k++){
    oa[2*k] = acc_a[k].x; oa[2*k+1] = acc_a[k].y;
    ob[2*k] = acc_b[k].x; ob[2*k+1] = acc_b[k].y;
  }
  *(half8*)ar = oa;
  *(half8*)(ar + 128) = ob;
  __syncthreads();
  if (wv >= 4) return;
  // MFMA epilogue: wave wv = output col-tile nt; A from LDS, Bp L2-hot
  int m = lane & 15, q = lane >> 4;
  const _Float16* arow = at + m*LRS + q*8;
  f32x4 cacc = (f32x4){0.f,0.f,0.f,0.f};
  #pragma unroll 4
  for (int kt = 0; kt < 32; kt++){
    half8 af = *(const half8*)(arow + kt*32);
    half8 bf = *(const half8*)(Bp + (((kt*4 + wv)*64 + lane) << 3));
    cacc = __builtin_amdgcn_mfma_f32_16x16x32_f16(af, bf, cacc, 0, 0, 0);
  }
  int c = wv*16 + m;
  float bb = b2[c];
  #pragma unroll
  for (int r = 0; r < 4; r++){
    int nrow = blockIdx.x*16 + q*4 + r;   // C/D: col=lane&15, row=(lane>>4)*4+reg [m89]
    outp[(size_t)nrow*64 + c] = cacc[r] + bb;
  }
}

extern "C" void kernel_launch(void* const* d_in, const int* in_sizes, int n_in,
                              void* d_out, int out_size, void* d_ws, size_t ws_size,
                              hipStream_t stream){
  const float* x   = (const float*)d_in[0];
  const int*   ei  = (const int*)d_in[1];
  const float* W1  = (const float*)d_in[2];
  const float* as1 = (const float*)d_in[3];
  const float* ad1 = (const float*)d_in[4];
  const float* b1  = (const float*)d_in[5];
  const float* W2  = (const float*)d_in[6];
  const float* as2 = (const float*)d_in[7];
  const float* ad2 = (const float*)d_in[8];
  const float* b2  = (const float*)d_in[9];
  float* outp = (float*)d_out;

  char* p = (char*)d_ws;
  auto alloc = [&](size_t bytes) -> void* {
    void* r = (void*)p;
    p += (bytes + 255) & ~(size_t)255;
    return r;
  };
  _Float16* h1  = (_Float16*)alloc((size_t)NPAD*128*2);          // [N,128] fp16
  _Float16* hr  = (_Float16*)alloc((size_t)N_NODES*128*2);       // [N,128] fp16
  float* als1 = (float*)alloc((size_t)N_NODES*8*4);
  float* ald1 = (float*)alloc((size_t)N_NODES*8*4);
  float* als2 = (float*)alloc((size_t)N_NODES*8*4);
  float* ald2 = (float*)alloc((size_t)N_NODES*8*4);
  int* row_ptr = (int*)alloc((size_t)(N_NODES+1)*4);
  int* deg  = (int*)alloc((size_t)N_NODES*4);
  int* cnt  = (int*)alloc((size_t)N_NODES*4);
  int* col  = (int*)alloc((size_t)ET*4);
  int* loc  = (int*)alloc((size_t)N_NODES*4);
  int* part = (int*)alloc(256*4);
  int* carry= (int*)alloc(256*4);
  int* flag = (int*)alloc(256);
  float* ws2 = (float*)alloc(1024*4);
  float* wd2 = (float*)alloc(1024*4);
  _Float16* Bp1 = (_Float16*)alloc((size_t)16384*2);
  _Float16* Bp  = (_Float16*)alloc((size_t)65536*2);

  dim3 b256(256);
  // launch 1: init + weight prep (independent block ranges)
  k_init_wprep<<<SCAN_NB + 324, b256, 0, stream>>>(ei, deg, cnt, flag,
                                                   W1, W2, as2, ad2,
                                                   Bp1, Bp, ws2, wd2);
  // launch 2: degree atomics || layer-1 GEMM (independent, overlapped)
  k_deg_gemm1<<<NB_DEG + NB_GEMM1, b256, 0, stream>>>(ei, deg, flag,
                                                      x, Bp1, h1, as1, ad1,
                                                      als1, ald1);
  // CSR scan + fill
  k_scan_part<<<SCAN_NB, b256, 0, stream>>>(deg, loc, part);
  k_scan_carry<<<1, b256, 0, stream>>>(part, carry);
  k_scan_add<<<SCAN_NB, b256, 0, stream>>>(loc, carry, row_ptr);
  k_fill<<<(ET+255)/256, b256, 0, stream>>>(ei, row_ptr, cnt, col, flag);
  // layer 1 softmax+agg (alpha2 fused)
  k_attn_agg1<<<N_NODES/4, b256, 0, stream>>>(h1, als1, ald1, row_ptr, col,
                                              b1, hr, ws2, wd2, als2, ald2);
  // layer 2: fused softmax+agg+output-GEMM
  k_attn_agg2<<<N_NODES/16, dim3(1024), 0, stream>>>(hr, als2, ald2, row_ptr, col,
                                                     Bp, b2, outp);
}

// Round 7
// 320.173 us; speedup vs baseline: 1.1388x; 1.0200x over previous
//
#include <hip/hip_runtime.h>

#define N_NODES 50000
#define N_EDGES 800000
#define ET (N_EDGES + N_NODES)   // 850000 incl. self loops
#define HEADS 8
#define NPAD 50048               // 782 blocks * 64 nodes
#define SCAN_NB 196              // ceil(50000/256)
#define CAP 96                   // LDS-cached edges per node (deg>CAP -> recompute)
#define LRS 1032                 // LDS A-tile row stride (halves, 16B-aligned)
#define NB_DEG 3321              // ceil(850000/256)
#define NB_GEMM1 782             // NPAD/64

typedef __attribute__((ext_vector_type(8))) _Float16 half8;
typedef __attribute__((ext_vector_type(2))) _Float16 half2v;
typedef __attribute__((ext_vector_type(4))) float f32x4;

// wave-local LDS fence: drains this wave's outstanding DS ops (same-wave
// cross-lane LDS write->read; consumers are ds_reads, ordered by "memory").
__device__ __forceinline__ void wave_lds_fence(){
  asm volatile("s_waitcnt lgkmcnt(0)" ::: "memory");
}

__device__ __forceinline__ int edge_src(const int* ei, int e, int is64){
  if (e >= N_EDGES) return e - N_EDGES;          // self loop
  return is64 ? ei[2*e] : ei[e];
}
__device__ __forceinline__ int edge_dst(const int* ei, int e, int is64){
  if (e >= N_EDGES) return e - N_EDGES;          // self loop
  return is64 ? ei[2*(N_EDGES + e)] : ei[N_EDGES + e];
}

// ======== launch 1: init (zero deg/cnt + layout probe) FUSED with wprep ========
// blocks [0,196): init; [196,452): W2 pack; [452,516): W1 pack; [516,520): wtilde
__global__ void k_init_wprep(const int* __restrict__ ei, int* __restrict__ deg,
                             int* __restrict__ cnt, int* __restrict__ flag,
                             const float* __restrict__ W1, const float* __restrict__ W2,
                             const float* __restrict__ as2, const float* __restrict__ ad2,
                             _Float16* __restrict__ Bp1, _Float16* __restrict__ Bp,
                             float* __restrict__ ws2, float* __restrict__ wd2){
  int b = blockIdx.x;
  int t_ = threadIdx.x;
  if (b < SCAN_NB){
    int i = b*256 + t_;
    if (i < N_NODES){ deg[i] = 0; cnt[i] = 0; }
    if (i == 0){
      int zeros = 0;
      for (int k = 0; k < 64; k++){
        if (ei[2*k + 1] == 0) zeros++;
      }
      *flag = (zeros >= 60) ? 1 : 0;   // 1 => int64 little-endian layout
    }
  } else if (b < SCAN_NB + 256){
    int t = (b - SCAN_NB)*256 + t_;
    int j = t & 7, lane = (t >> 3) & 63, nt = (t >> 9) & 3, kt = t >> 11;
    int k = kt*32 + (lane >> 4)*8 + j;
    int c = nt*16 + (lane & 15);
    int h = k >> 7, kk = k & 127;
    Bp[t] = (_Float16)(0.125f * W2[kk*512 + h*64 + c]);
  } else if (b < SCAN_NB + 320){
    int t = (b - SCAN_NB - 256)*256 + t_;
    int j = t & 7, lane = (t >> 3) & 63, nt = (t >> 9) & 7, kt = t >> 12;
    int k = kt*32 + (lane >> 4)*8 + j;
    int c = nt*16 + (lane & 15);
    Bp1[t] = (_Float16)W1[k*128 + c];
  } else {
    int t = (b - SCAN_NB - 320)*256 + t_;
    int k = t >> 3, h = t & 7;
    float s = 0.f, d = 0.f;
    for (int dd = 0; dd < 64; dd++){
      float w = W2[k*512 + h*64 + dd];
      s += w * as2[h*64 + dd];
      d += w * ad2[h*64 + dd];
    }
    ws2[h*128 + k] = s;
    wd2[h*128 + k] = d;
  }
}

// ======== launch 2: degree histogram FUSED with layer-1 GEMM (independent) ========
// blocks [0,NB_DEG): degree atomics; [NB_DEG, NB_DEG+NB_GEMM1): h1 = x@W1 + alpha1.
__global__ void __launch_bounds__(256) k_deg_gemm1(
    const int* __restrict__ ei, int* __restrict__ deg, const int* __restrict__ flag,
    const float* __restrict__ x, const _Float16* __restrict__ Bp1,
    _Float16* __restrict__ h1,
    const float* __restrict__ as1, const float* __restrict__ ad1,
    float* __restrict__ als1, float* __restrict__ ald1){
  if (blockIdx.x < NB_DEG){
    int e = blockIdx.x*blockDim.x + threadIdx.x;
    if (e >= ET) return;
    int is64 = *flag;
    int d = edge_dst(ei, e, is64);
    atomicAdd(&deg[d], 1);
    return;
  }
  int bid = blockIdx.x - NB_DEG;
  int tid = threadIdx.x;
  int lane = tid & 63, wv = tid >> 6;
  int n0 = bid*64 + wv*16;
  int rowA = n0 + (lane & 15);
  int koff = (lane >> 4)*8;
  const float* xr = x + (size_t)rowA*128 + koff;
  f32x4 acc[8];
  #pragma unroll
  for (int i = 0; i < 8; i++) acc[i] = (f32x4){0.f,0.f,0.f,0.f};
  bool inb = (rowA < N_NODES);
  #pragma unroll
  for (int kt = 0; kt < 4; kt++){
    half8 af;
    if (inb){
      float4 a0 = *(const float4*)(xr + kt*32);
      float4 a1 = *(const float4*)(xr + kt*32 + 4);
      af = (half8){(_Float16)a0.x,(_Float16)a0.y,(_Float16)a0.z,(_Float16)a0.w,
                   (_Float16)a1.x,(_Float16)a1.y,(_Float16)a1.z,(_Float16)a1.w};
    } else {
      af = (half8){0,0,0,0,0,0,0,0};
    }
    #pragma unroll
    for (int nt = 0; nt < 8; nt++){
      half8 bf = *(const half8*)(Bp1 + (((kt*8 + nt)*64 + lane) << 3));
      acc[nt] = __builtin_amdgcn_mfma_f32_16x16x32_f16(af, bf, acc[nt], 0, 0, 0);
    }
  }
  int m = lane & 15, q = lane >> 4;
  int r0 = n0 + q*4;               // C/D: col=lane&15, row=(lane>>4)*4+reg  [m89]
  #pragma unroll
  for (int nt = 0; nt < 8; nt++){
    int c = nt*16 + m;
    #pragma unroll
    for (int r = 0; r < 4; r++){
      int n = r0 + r;
      if (n < N_NODES) h1[(size_t)n*128 + c] = (_Float16)acc[nt][r];
    }
  }
  // fused alpha1: lane's acc[nt][r] is channel (nt*16+m) == head nt, pos m of row r0+r
  float as1v[8], ad1v[8];
  #pragma unroll
  for (int nt = 0; nt < 8; nt++){
    as1v[nt] = as1[nt*16 + m];
    ad1v[nt] = ad1[nt*16 + m];
  }
  #pragma unroll
  for (int r = 0; r < 4; r++){
    float vs[8], vd[8];
    #pragma unroll
    for (int nt = 0; nt < 8; nt++){
      vs[nt] = acc[nt][r]*as1v[nt];
      vd[nt] = acc[nt][r]*ad1v[nt];
      #pragma unroll
      for (int off = 1; off < 16; off <<= 1){
        vs[nt] += __shfl_xor(vs[nt], off, 64);
        vd[nt] += __shfl_xor(vd[nt], off, 64);
      }
    }
    int n = r0 + r;
    if (m == r && n < N_NODES){
      float4 v0; v0.x = vs[0]; v0.y = vs[1]; v0.z = vs[2]; v0.w = vs[3];
      float4 v1; v1.x = vs[4]; v1.y = vs[5]; v1.z = vs[6]; v1.w = vs[7];
      float4 w0; w0.x = vd[0]; w0.y = vd[1]; w0.z = vd[2]; w0.w = vd[3];
      float4 w1; w1.x = vd[4]; w1.y = vd[5]; w1.z = vd[6]; w1.w = vd[7];
      *(float4*)&als1[n*8]     = v0;
      *(float4*)&als1[n*8 + 4] = v1;
      *(float4*)&ald1[n*8]     = w0;
      *(float4*)&ald1[n*8 + 4] = w1;
    }
  }
}

// ---- 3-stage scan ----
__global__ void k_scan_part(const int* __restrict__ deg, int* __restrict__ loc,
                            int* __restrict__ part){
  __shared__ int lds[256];
  int t = threadIdx.x, i = blockIdx.x*256 + t;
  int v = (i < N_NODES) ? deg[i] : 0;
  lds[t] = v;
  __syncthreads();
  for (int off = 1; off < 256; off <<= 1){
    int x = (t >= off) ? lds[t - off] : 0;
    __syncthreads();
    lds[t] += x;
    __syncthreads();
  }
  if (i < N_NODES) loc[i] = lds[t] - v;          // local exclusive
  if (t == 255) part[blockIdx.x] = lds[255];
}

__global__ void k_scan_carry(int* __restrict__ part, int* __restrict__ carry){
  __shared__ int lds[256];
  int t = threadIdx.x;
  int v = (t < SCAN_NB) ? part[t] : 0;
  lds[t] = v;
  __syncthreads();
  for (int off = 1; off < 256; off <<= 1){
    int x = (t >= off) ? lds[t - off] : 0;
    __syncthreads();
    lds[t] += x;
    __syncthreads();
  }
  if (t < SCAN_NB) carry[t] = lds[t] - v;        // exclusive over blocks
}

__global__ void k_scan_add(const int* __restrict__ loc, const int* __restrict__ carry,
                           int* __restrict__ row_ptr){
  int i = blockIdx.x*blockDim.x + threadIdx.x;
  if (i < N_NODES) row_ptr[i] = loc[i] + carry[i >> 8];
  if (i == 0) row_ptr[N_NODES] = ET;
}

__global__ void k_fill(const int* __restrict__ ei, const int* __restrict__ row_ptr,
                       int* __restrict__ cnt, int* __restrict__ col,
                       const int* __restrict__ flag){
  int e = blockIdx.x*blockDim.x + threadIdx.x;
  if (e >= ET) return;
  int is64 = *flag;
  int s = edge_src(ei, e, is64);
  int d = edge_dst(ei, e, is64);
  int pos = atomicAdd(&cnt[d], 1);
  col[row_ptr[d] + pos] = s;
}

// ===== layer 1: two-phase softmax+agg; WIDE phase-2 gather =====
// Phase 2 lane map (eg=lane>>4, cb=lane&15): lane handles edge j+eg, channels
// [cb*8,cb*8+8) (head hq=cb>>1) -> ONE half8 (dwordx4) load per 4 edges per lane
// (4x fewer VMEM instrs than the half2-per-lane layout); fp32 acc; cross-eg
// shfl reduce at the end. No cross-wave barrier (per-wave LDS + fence only).
__global__ void k_attn_agg1(const _Float16* __restrict__ h1,
    const float* __restrict__ als, const float* __restrict__ ald,
    const int* __restrict__ row_ptr, const int* __restrict__ col,
    const float* __restrict__ bias, _Float16* __restrict__ hr,
    const float* __restrict__ ws2, const float* __restrict__ wd2,
    float* __restrict__ als2, float* __restrict__ ald2){
  __shared__ _Float16 ew_s[4][CAP*8];
  __shared__ int col_s[4][CAP];
  __shared__ _Float16 ot_s[4][136];
  int tid = threadIdx.x;
  int wv = tid >> 6, lane = tid & 63;
  int n = blockIdx.x*4 + wv;              // grid exact: 12500*4 = 50000
  int beg = row_ptr[n], end = row_ptr[n+1];
  int deg = end - beg;
  int items = deg*8;
  int h = lane & 7;
  float ad = ald[n*8 + h];
  _Float16* es = ew_s[wv];
  int* cs = col_s[wv];
  float l = 0.f;
  int itc = items < CAP*8 ? items : CAP*8;
  int it = lane;
  for (; it < itc; it += 64){             // cached range: store es + col
    int e = it >> 3;
    int s = col[beg + e];
    float a = als[s*8 + h] + ad;
    a = (a > 0.f) ? a : 0.2f*a;
    float ex = __expf(a);
    es[it] = (_Float16)ex;
    if ((it & 7) == 0) cs[e] = s;
    l += ex;
  }
  for (; it < items; it += 64){           // rare overflow range
    int s = col[beg + (it >> 3)];
    float a = als[s*8 + h] + ad;
    a = (a > 0.f) ? a : 0.2f*a;
    l += __expf(a);
  }
  l += __shfl_xor(l, 8, 64);
  l += __shfl_xor(l, 16, 64);
  l += __shfl_xor(l, 32, 64);
  float inv = 1.f / (l + 1e-16f);
  wave_lds_fence();                       // own-wave LDS only: no __syncthreads
  // ---- phase 2: wide gather ----
  int eg = lane >> 4, cb = lane & 15;
  int hq = cb >> 1;                       // head owning channels cb*8..cb*8+7
  float invh = __shfl(inv, hq, 64);
  float adh  = __shfl(ad, hq, 64);        // ald[n*8+hq] (for overflow path)
  float acc[8];
  #pragma unroll
  for (int k = 0; k < 8; k++) acc[k] = 0.f;
  int degc = deg < CAP ? deg : CAP;
  int j = 0;
  for (; j + 3 < degc; j += 4){
    int e = j + eg;
    int s = cs[e];
    float w = (float)es[e*8 + hq] * invh;
    half8 v = *(const half8*)(h1 + (size_t)s*128 + cb*8);
    #pragma unroll
    for (int k = 0; k < 8; k++) acc[k] += w*(float)v[k];
  }
  if (j < degc){                          // tail (predicated, <=3 edges)
    int e = j + eg;
    if (e < degc){
      int s = cs[e];
      float w = (float)es[e*8 + hq] * invh;
      half8 v = *(const half8*)(h1 + (size_t)s*128 + cb*8);
      #pragma unroll
      for (int k = 0; k < 8; k++) acc[k] += w*(float)v[k];
    }
  }
  for (int jj = degc; jj < deg; jj += 4){ // rare: deg > CAP, recompute weights
    int e = jj + eg;
    if (e < deg){
      int s = col[beg + e];
      float a = als[s*8 + hq] + adh;
      a = (a > 0.f) ? a : 0.2f*a;
      float w = __expf(a)*invh;
      half8 v = *(const half8*)(h1 + (size_t)s*128 + cb*8);
      #pragma unroll
      for (int k = 0; k < 8; k++) acc[k] += w*(float)v[k];
    }
  }
  // cross-eg reduce (4 edge groups)
  #pragma unroll
  for (int k = 0; k < 8; k++){
    acc[k] += __shfl_xor(acc[k], 16, 64);
    acc[k] += __shfl_xor(acc[k], 32, 64);
  }
  // bias + ReLU; lanes eg==0 write the full row (16 lanes x 16B, coalesced)
  float4 b0 = *(const float4*)(bias + cb*8);
  float4 b1 = *(const float4*)(bias + cb*8 + 4);
  float bb[8] = {b0.x,b0.y,b0.z,b0.w,b1.x,b1.y,b1.z,b1.w};
  half8 oh;
  #pragma unroll
  for (int k = 0; k < 8; k++) oh[k] = (_Float16)fmaxf(acc[k] + bb[k], 0.f);
  if (eg == 0){
    *(half8*)(hr + (size_t)n*128 + cb*8) = oh;
    ((half8*)&ot_s[wv][0])[cb] = oh;      // same-wave LDS transpose staging
  }
  wave_lds_fence();
  // fused alpha2: lane -> (head hh=lane>>3, segment seg=lane&7)
  int hh = lane >> 3, seg = lane & 7;
  const half2v* otp = (const half2v*)&ot_s[wv][0];
  const float* wsr = ws2 + hh*128 + seg*16;
  const float* wdr = wd2 + hh*128 + seg*16;
  float vs = 0.f, vd = 0.f;
  #pragma unroll
  for (int i = 0; i < 8; i++){
    half2v v = otp[seg*8 + i];
    float vx = (float)v.x, vy = (float)v.y;
    vs += vx*wsr[2*i] + vy*wsr[2*i + 1];
    vd += vx*wdr[2*i] + vy*wdr[2*i + 1];
  }
  vs += __shfl_xor(vs, 1, 64); vd += __shfl_xor(vd, 1, 64);
  vs += __shfl_xor(vs, 2, 64); vd += __shfl_xor(vd, 2, 64);
  vs += __shfl_xor(vs, 4, 64); vd += __shfl_xor(vd, 4, 64);
  if (seg == 0){
    als2[n*8 + hh] = vs;
    ald2[n*8 + hh] = vd;
  }
}

// ===== layer 2 FUSED: softmax+agg (16 waves = 16 nodes) + output MFMA GEMM =====
// Two-phase with LDS exp table (dedups exps 16x vs single-pass, R4 lesson);
// mid barrier = wave-local fence; phase-2 unroll-4 (28 VGPR sweet spot, R5 lesson).
__global__ void __launch_bounds__(1024) k_attn_agg2(const _Float16* __restrict__ hr,
    const float* __restrict__ als, const float* __restrict__ ald,
    const int* __restrict__ row_ptr, const int* __restrict__ col,
    const _Float16* __restrict__ Bp, const float* __restrict__ b2,
    float* __restrict__ outp){
  __shared__ _Float16 ew_s[16][CAP*8];
  __shared__ int col_s[16][CAP];
  __shared__ _Float16 at[16*LRS];
  int tid = threadIdx.x;
  int wv = tid >> 6, lane = tid & 63;
  int n = blockIdx.x*16 + wv;             // grid exact: 3125*16 = 50000
  int beg = row_ptr[n], end = row_ptr[n+1];
  int deg = end - beg;
  int items = deg*8;
  int h = lane & 7;
  float ad = ald[n*8 + h];
  _Float16* es = ew_s[wv];
  int* cs = col_s[wv];
  float l = 0.f;
  int itc = items < CAP*8 ? items : CAP*8;
  int it = lane;
  for (; it < itc; it += 64){
    int e = it >> 3;
    int s = col[beg + e];
    float a = als[s*8 + h] + ad;
    a = (a > 0.f) ? a : 0.2f*a;
    float ex = __expf(a);
    es[it] = (_Float16)ex;
    if ((it & 7) == 0) cs[e] = s;
    l += ex;
  }
  for (; it < items; it += 64){
    int s = col[beg + (it >> 3)];
    float a = als[s*8 + h] + ad;
    a = (a > 0.f) ? a : 0.2f*a;
    l += __expf(a);
  }
  l += __shfl_xor(l, 8, 64);
  l += __shfl_xor(l, 16, 64);
  l += __shfl_xor(l, 32, 64);
  float inv = 1.f / (l + 1e-16f);   // for head lane&7 (lanes with same lane&7 agree)
  wave_lds_fence();                 // own-wave LDS only: no cross-wave barrier here
  int hp = lane >> 4, cb = lane & 15;
  float invA = __shfl(inv, 2*hp, 64);       // inv for head 2hp   (held by lane 2hp)
  float invB = __shfl(inv, 2*hp + 1, 64);   // inv for head 2hp+1
  half2v inv2; inv2.x = (_Float16)invA; inv2.y = (_Float16)invB;
  half2v acc_a[4], acc_b[4];
  #pragma unroll
  for (int i = 0; i < 4; i++){
    acc_a[i] = (half2v){(_Float16)0.f, (_Float16)0.f};
    acc_b[i] = (half2v){(_Float16)0.f, (_Float16)0.f};
  }
  int degc = deg < CAP ? deg : CAP;
  const _Float16* esw = es + 2*hp;          // per-lane weight base (both heads, u32)
  int j = 0;
  for (; j + 3 < degc; j += 4){
    int s0 = cs[j], s1 = cs[j+1], s2 = cs[j+2], s3 = cs[j+3];
    half2v w0 = *(const half2v*)(esw + (j+0)*8) * inv2;
    half2v w1 = *(const half2v*)(esw + (j+1)*8) * inv2;
    half2v w2 = *(const half2v*)(esw + (j+2)*8) * inv2;
    half2v w3 = *(const half2v*)(esw + (j+3)*8) * inv2;
    half8 v0 = *(const half8*)(hr + (size_t)s0*128 + cb*8);
    half8 v1 = *(const half8*)(hr + (size_t)s1*128 + cb*8);
    half8 v2 = *(const half8*)(hr + (size_t)s2*128 + cb*8);
    half8 v3 = *(const half8*)(hr + (size_t)s3*128 + cb*8);
    #pragma unroll
    for (int k = 0; k < 4; k++){
      half2v t;
      t = (half2v){v0[2*k], v0[2*k+1]};
      acc_a[k] += (half2v){w0.x, w0.x} * t;
      acc_b[k] += (half2v){w0.y, w0.y} * t;
      t = (half2v){v1[2*k], v1[2*k+1]};
      acc_a[k] += (half2v){w1.x, w1.x} * t;
      acc_b[k] += (half2v){w1.y, w1.y} * t;
      t = (half2v){v2[2*k], v2[2*k+1]};
      acc_a[k] += (half2v){w2.x, w2.x} * t;
      acc_b[k] += (half2v){w2.y, w2.y} * t;
      t = (half2v){v3[2*k], v3[2*k+1]};
      acc_a[k] += (half2v){w3.x, w3.x} * t;
      acc_b[k] += (half2v){w3.y, w3.y} * t;
    }
  }
  for (; j < degc; j++){
    int s = cs[j];
    half2v w = *(const half2v*)(esw + j*8) * inv2;
    half8 v = *(const half8*)(hr + (size_t)s*128 + cb*8);
    #pragma unroll
    for (int k = 0; k < 4; k++){
      half2v t = (half2v){v[2*k], v[2*k+1]};
      acc_a[k] += (half2v){w.x, w.x} * t;
      acc_b[k] += (half2v){w.y, w.y} * t;
    }
  }
  if (deg > CAP){                             // rare: deg > CAP, recompute weights
    float2 adv = *(const float2*)(ald + (size_t)n*8 + 2*hp);
    for (; j < deg; j++){
      int s = col[beg + j];
      float2 alv = *(const float2*)(als + (size_t)s*8 + 2*hp);
      float a0 = alv.x + adv.x; a0 = (a0 > 0.f) ? a0 : 0.2f*a0;
      float a1 = alv.y + adv.y; a1 = (a1 > 0.f) ? a1 : 0.2f*a1;
      _Float16 w0 = (_Float16)(__expf(a0)*invA);
      _Float16 w1 = (_Float16)(__expf(a1)*invB);
      half8 v = *(const half8*)(hr + (size_t)s*128 + cb*8);
      #pragma unroll
      for (int k = 0; k < 4; k++){
        half2v t = (half2v){v[2*k], v[2*k+1]};
        acc_a[k] += (half2v){w0, w0} * t;
        acc_b[k] += (half2v){w1, w1} * t;
      }
    }
  }
  // write normalized rows into the LDS A-tile: head 2hp and 2hp+1, channels cb*8..
  _Float16* ar = at + wv*LRS + (2*hp)*128 + cb*8;
  half8 oa, ob;
  #pragma unroll
  for (int k = 0; k < 4; k++){
    oa[2*k] = acc_a[k].x; oa[2*k+1] = acc_a[k].y;
    ob[2*k] = acc_b[k].x; ob[2*k+1] = acc_b[k].y;
  }
  *(half8*)ar = oa;
  *(half8*)(ar + 128) = ob;
  __syncthreads();
  if (wv >= 4) return;
  // MFMA epilogue: wave wv = output col-tile nt; A from LDS, Bp L2-hot
  int m = lane & 15, q = lane >> 4;
  const _Float16* arow = at + m*LRS + q*8;
  f32x4 cacc = (f32x4){0.f,0.f,0.f,0.f};
  #pragma unroll 4
  for (int kt = 0; kt < 32; kt++){
    half8 af = *(const half8*)(arow + kt*32);
    half8 bf = *(const half8*)(Bp + (((kt*4 + wv)*64 + lane) << 3));
    cacc = __builtin_amdgcn_mfma_f32_16x16x32_f16(af, bf, cacc, 0, 0, 0);
  }
  int c = wv*16 + m;
  float bb = b2[c];
  #pragma unroll
  for (int r = 0; r < 4; r++){
    int nrow = blockIdx.x*16 + q*4 + r;   // C/D: col=lane&15, row=(lane>>4)*4+reg [m89]
    outp[(size_t)nrow*64 + c] = cacc[r] + bb;
  }
}

extern "C" void kernel_launch(void* const* d_in, const int* in_sizes, int n_in,
                              void* d_out, int out_size, void* d_ws, size_t ws_size,
                              hipStream_t stream){
  const float* x   = (const float*)d_in[0];
  const int*   ei  = (const int*)d_in[1];
  const float* W1  = (const float*)d_in[2];
  const float* as1 = (const float*)d_in[3];
  const float* ad1 = (const float*)d_in[4];
  const float* b1  = (const float*)d_in[5];
  const float* W2  = (const float*)d_in[6];
  const float* as2 = (const float*)d_in[7];
  const float* ad2 = (const float*)d_in[8];
  const float* b2  = (const float*)d_in[9];
  float* outp = (float*)d_out;

  char* p = (char*)d_ws;
  auto alloc = [&](size_t bytes) -> void* {
    void* r = (void*)p;
    p += (bytes + 255) & ~(size_t)255;
    return r;
  };
  _Float16* h1  = (_Float16*)alloc((size_t)NPAD*128*2);          // [N,128] fp16
  _Float16* hr  = (_Float16*)alloc((size_t)N_NODES*128*2);       // [N,128] fp16
  float* als1 = (float*)alloc((size_t)N_NODES*8*4);
  float* ald1 = (float*)alloc((size_t)N_NODES*8*4);
  float* als2 = (float*)alloc((size_t)N_NODES*8*4);
  float* ald2 = (float*)alloc((size_t)N_NODES*8*4);
  int* row_ptr = (int*)alloc((size_t)(N_NODES+1)*4);
  int* deg  = (int*)alloc((size_t)N_NODES*4);
  int* cnt  = (int*)alloc((size_t)N_NODES*4);
  int* col  = (int*)alloc((size_t)ET*4);
  int* loc  = (int*)alloc((size_t)N_NODES*4);
  int* part = (int*)alloc(256*4);
  int* carry= (int*)alloc(256*4);
  int* flag = (int*)alloc(256);
  float* ws2 = (float*)alloc(1024*4);
  float* wd2 = (float*)alloc(1024*4);
  _Float16* Bp1 = (_Float16*)alloc((size_t)16384*2);
  _Float16* Bp  = (_Float16*)alloc((size_t)65536*2);

  dim3 b256(256);
  // launch 1: init + weight prep (independent block ranges)
  k_init_wprep<<<SCAN_NB + 324, b256, 0, stream>>>(ei, deg, cnt, flag,
                                                   W1, W2, as2, ad2,
                                                   Bp1, Bp, ws2, wd2);
  // launch 2: degree atomics || layer-1 GEMM (independent, overlapped)
  k_deg_gemm1<<<NB_DEG + NB_GEMM1, b256, 0, stream>>>(ei, deg, flag,
                                                      x, Bp1, h1, as1, ad1,
                                                      als1, ald1);
  // CSR scan + fill
  k_scan_part<<<SCAN_NB, b256, 0, stream>>>(deg, loc, part);
  k_scan_carry<<<1, b256, 0, stream>>>(part, carry);
  k_scan_add<<<SCAN_NB, b256, 0, stream>>>(loc, carry, row_ptr);
  k_fill<<<(ET+255)/256, b256, 0, stream>>>(ei, row_ptr, cnt, col, flag);
  // layer 1 softmax+agg (alpha2 fused)
  k_attn_agg1<<<N_NODES/4, b256, 0, stream>>>(h1, als1, ald1, row_ptr, col,
                                              b1, hr, ws2, wd2, als2, ald2);
  // layer 2: fused softmax+agg+output-GEMM
  k_attn_agg2<<<N_NODES/16, dim3(1024), 0, stream>>>(hr, als2, ald2, row_ptr, col,
                                                     Bp, b2, outp);
}